// Round 5
// baseline (193.965 us; speedup 1.0000x reference)
//
#include <hip/hip_runtime.h>
#include <hip/hip_bf16.h>

// GAT layer, MI355X. B=32, N=512, Fin=256, F=64, H=8. fp32 in / fp32 out.
// R11 = R10 split (k2 isolated at 71.4us; VALU 21.5%/MFMA 5.4%/HBM 10.4%/
// bank-conflict 0 => in-loop latency serialization) + ONE fix in both kernels:
// make every global load older than everything in flight when consumed, so
// the compiler can emit COUNTED s_waitcnt vmcnt(N) instead of vmcnt(0).
//   R10's loop consumed bv (hT) the same iteration it was issued (after the
//   adj prefetch) -> waiting for bv forces vmcnt(0) -> the adj "prefetch"
//   was drained every iteration; ~10 serialized latencies/iter = 10.7k cyc.
//   Now: bv double-buffered (issued 1 iter ahead), adj ring depth-2 (issued
//   2 iters ahead), static even/odd unroll (no runtime-indexed regs), tails
//   clamped in-bounds. k1 gets the same treatment for its x-loads + q=2 grid
//   split (2 blocks/CU, 16 waves/CU).
// Fallback: if ws_size < 17.8MB, launch the proven R8 fused kernel.

#define ALPHA  0.2f
#define ESCALE 1.4426950408889634f   // log2(e), folded into a at stage 0

typedef __bf16 bf16x8 __attribute__((ext_vector_type(8)));
typedef __bf16 bf16x4 __attribute__((ext_vector_type(4)));
typedef float  f32x4  __attribute__((ext_vector_type(4)));

#if __has_builtin(__builtin_amdgcn_exp2f)
#define EXP2(x) __builtin_amdgcn_exp2f(x)
#else
#define EXP2(x) exp2f(x)
#endif

#define HT_STRIDE 520   // fused-fallback only
#define WT_STRIDE 264   // 256+8

__device__ inline bf16x8 ld8(const float* p) {
    float4 a0 = *(const float4*)p;
    float4 a1 = *(const float4*)(p + 4);
    bf16x8 r;
    r[0]=(__bf16)a0.x; r[1]=(__bf16)a0.y; r[2]=(__bf16)a0.z; r[3]=(__bf16)a0.w;
    r[4]=(__bf16)a1.x; r[5]=(__bf16)a1.y; r[6]=(__bf16)a1.z; r[7]=(__bf16)a1.w;
    return r;
}

// ---------------- k1: h = x@W (bf16 hT to ws) + scores ---------------------
struct SmemK1 {
    __bf16 WT[64][WT_STRIDE];       // 33,792 B
    float  asrc[64], adst[64];      //    512 B
};                                  // 34,304 B

// one K-step: issue next raw x-loads, then consume current (counted vmcnt)
#define K1BODY(KS, RAWC, RAWN)                                                 \
    {                                                                          \
        const int kpf = ((KS) + 1 < 8) ? ((KS) + 1) * 32 + quad * 8            \
                                       : quad * 8;                             \
        _Pragma("unroll")                                                      \
        for (int it = 0; it < 2; ++it) {                                       \
            RAWN[it][0] = *(const float4*)(xrow[it] + kpf);                    \
            RAWN[it][1] = *(const float4*)(xrow[it] + kpf + 4);                \
        }                                                                      \
        const int k0 = (KS) * 32 + quad * 8;                                   \
        bf16x8 bv[4];                                                          \
        _Pragma("unroll")                                                      \
        for (int nt = 0; nt < 4; ++nt)                                         \
            bv[nt] = *(const bf16x8*)(&sm.WT[nt * 16 + col][k0]);              \
        bf16x8 av[2];                                                          \
        _Pragma("unroll")                                                      \
        for (int it = 0; it < 2; ++it) {                                       \
            av[it][0]=(__bf16)RAWC[it][0].x; av[it][1]=(__bf16)RAWC[it][0].y;  \
            av[it][2]=(__bf16)RAWC[it][0].z; av[it][3]=(__bf16)RAWC[it][0].w;  \
            av[it][4]=(__bf16)RAWC[it][1].x; av[it][5]=(__bf16)RAWC[it][1].y;  \
            av[it][6]=(__bf16)RAWC[it][1].z; av[it][7]=(__bf16)RAWC[it][1].w;  \
        }                                                                      \
        _Pragma("unroll")                                                      \
        for (int it = 0; it < 2; ++it)                                         \
            _Pragma("unroll")                                                  \
            for (int nt = 0; nt < 4; ++nt)                                     \
                acc[it][nt] = __builtin_amdgcn_mfma_f32_16x16x32_bf16(av[it], bv[nt], acc[it][nt], 0, 0, 0); \
    }

__global__ __launch_bounds__(512, 4) void k1_gemm(const float* __restrict__ x,
                                                  const float* __restrict__ W,
                                                  const float* __restrict__ a,
                                                  __bf16* __restrict__ hT,
                                                  float* __restrict__ ssrc,
                                                  float* __restrict__ sdst) {
    __shared__ SmemK1 sm;
    const int b = blockIdx.x, h = blockIdx.y, qq = blockIdx.z; // b-major: XCD=b%8
    const int tid  = threadIdx.x;                // 512 thr, 8 waves
    const int wave = tid >> 6, lane = tid & 63;
    const int quad = lane >> 4, col = lane & 15;

    // stage 0: a * log2e -> LDS; W head-slice fp32->bf16 -> LDS
    if (tid < 128) {
        float v = a[h * 128 + tid] * ESCALE;
        if (tid < 64) sm.asrc[tid] = v; else sm.adst[tid - 64] = v;
    }
    {
        int c = tid & 63, k0 = tid >> 6;
        #pragma unroll 4
        for (int t = 0; t < 32; ++t)
            sm.WT[c][k0 + t * 8] = (__bf16)W[(long)(k0 + t * 8) * 512 + h * 64 + c];
    }
    __syncthreads();                             // only barrier in k1

    // stage 1: MFMA over this block's 256 rows; wave owns 32 rows (it=2)
    const int rbase = qq * 256 + wave * 32;
    const float* xb = x + (long)b * 512 * 256;
    const float* xrow[2];
    #pragma unroll
    for (int it = 0; it < 2; ++it)
        xrow[it] = xb + (long)(rbase + it * 16 + col) * 256;

    f32x4 acc[2][4] = {};
    float4 rawA[2][2], rawB[2][2];
    #pragma unroll
    for (int it = 0; it < 2; ++it) {             // prologue: raw x for ks=0
        rawA[it][0] = *(const float4*)(xrow[it] + quad * 8);
        rawA[it][1] = *(const float4*)(xrow[it] + quad * 8 + 4);
    }
    for (int ks = 0; ks < 8; ks += 2) {          // K = 256, static dbuf swap
        K1BODY(ks,     rawA, rawB)
        K1BODY(ks + 1, rawB, rawA)
    }

    // write hT[f][j] bf16 to ws: f = nt*16+col, j = rbase+it*16+quad*4 (+r)
    const long bh = (long)b * 8 + h;
    {
        #pragma unroll
        for (int it = 0; it < 2; ++it)
            #pragma unroll
            for (int nt = 0; nt < 4; ++nt) {
                int f = nt * 16 + col;
                int j = rbase + it * 16 + quad * 4;
                bf16x4 pk = { (__bf16)acc[it][nt][0], (__bf16)acc[it][nt][1],
                              (__bf16)acc[it][nt][2], (__bf16)acc[it][nt][3] };
                *(bf16x4*)(hT + (bh * 64 + f) * 512 + j) = pk;
            }
    }

    // scores from fp32 fragments: s[j] = sum_f h[j][f]*a[f]
    {
        float asr[4], adr[4];
        #pragma unroll
        for (int nt = 0; nt < 4; ++nt) {
            asr[nt] = sm.asrc[nt * 16 + col];
            adr[nt] = sm.adst[nt * 16 + col];
        }
        #pragma unroll
        for (int it = 0; it < 2; ++it)
            #pragma unroll
            for (int r = 0; r < 4; ++r) {
                float ps = 0.f, pd = 0.f;
                #pragma unroll
                for (int nt = 0; nt < 4; ++nt) {
                    ps += acc[it][nt][r] * asr[nt];
                    pd += acc[it][nt][r] * adr[nt];
                }
                // butterfly over the 16 col-lanes (stays within quad)
                #pragma unroll
                for (int m = 1; m <= 8; m <<= 1) {
                    ps += __shfl_xor(ps, m, 64);
                    pd += __shfl_xor(pd, m, 64);
                }
                if (col == 0) {
                    int j = rbase + it * 16 + quad * 4 + r;
                    ssrc[bh * 512 + j] = ps;
                    sdst[bh * 512 + j] = pd;
                }
            }
    }
}

// ---------------- k2: stage 3 (attention + P@h) ----------------------------
// one neighbor-step: consume pa_cur (issued 2 iters ago) + bv_cur (1 iter
// ago); issue pa(ks+2) into the SAME ring slot and bv(ks+1) into the other
// buffer BEFORE the MFMA -> compiler can wait with counted vmcnt, never 0.
#define K2BODY(KS, PAC0, PAC1, BVC, BVN)                                       \
    {                                                                          \
        const int j0 = (KS) * 32 + quad * 8;                                   \
        f32x4 s0 = *(const f32x4*)&sds[j0];                                    \
        f32x4 s1 = *(const f32x4*)&sds[j0 + 4];                                \
        float sd[8] = {s0[0],s0[1],s0[2],s0[3],s1[0],s1[1],s1[2],s1[3]};       \
        float am[2][8];                                                        \
        _Pragma("unroll")                                                      \
        for (int it = 0; it < 2; ++it) {                                       \
            am[it][0]=PAC0[it].x; am[it][1]=PAC0[it].y;                        \
            am[it][2]=PAC0[it].z; am[it][3]=PAC0[it].w;                        \
            am[it][4]=PAC1[it].x; am[it][5]=PAC1[it].y;                        \
            am[it][6]=PAC1[it].z; am[it][7]=PAC1[it].w;                        \
        }                                                                      \
        const int jpf = ((KS) + 2 < 16) ? ((KS) + 2) * 32 + quad * 8           \
                                        : quad * 8;                            \
        _Pragma("unroll")                                                      \
        for (int it = 0; it < 2; ++it) {                                       \
            PAC0[it] = *(const float4*)(arow[it] + jpf);                       \
            PAC1[it] = *(const float4*)(arow[it] + jpf + 4);                   \
        }                                                                      \
        const int jbv = ((KS) + 1 < 16) ? ((KS) + 1) * 32 + quad * 8           \
                                        : quad * 8;                            \
        _Pragma("unroll")                                                      \
        for (int nt = 0; nt < 4; ++nt)                                         \
            BVN[nt] = *(const bf16x8*)(hTb + (long)(nt * 16 + col) * 512 + jbv);\
        bf16x8 P[2];                                                           \
        _Pragma("unroll")                                                      \
        for (int it = 0; it < 2; ++it)                                         \
            _Pragma("unroll")                                                  \
            for (int u = 0; u < 8; ++u) {                                      \
                float e = si[it] + sd[u];                                      \
                float l = fmaxf(e, ALPHA * e);                                 \
                float p = am[it][u] * EXP2(l);                                 \
                P[it][u] = (__bf16)p;                                          \
            }                                                                  \
        _Pragma("unroll")                                                      \
        for (int it = 0; it < 2; ++it) {                                       \
            _Pragma("unroll")                                                  \
            for (int nt = 0; nt < 4; ++nt)                                     \
                acc[it][nt] = __builtin_amdgcn_mfma_f32_16x16x32_bf16(P[it], BVC[nt], acc[it][nt], 0, 0, 0); \
            accs[it] = __builtin_amdgcn_mfma_f32_16x16x32_bf16(P[it], ones, accs[it], 0, 0, 0); \
        }                                                                      \
    }

__global__ __launch_bounds__(256, 4) void k2_attn(const float* __restrict__ adj,
                                                  const __bf16* __restrict__ hT,
                                                  const float* __restrict__ ssrc,
                                                  const float* __restrict__ sdst,
                                                  float* __restrict__ out) {
    __shared__ float sds[512];                   // 2 KB
    const int b = blockIdx.x, h = blockIdx.y, q = blockIdx.z;
    const int tid  = threadIdx.x;                // 256 thr, 4 waves
    const int wave = tid >> 6, lane = tid & 63;
    const int quad = lane >> 4, col = lane & 15;
    const long bh = (long)b * 8 + h;
    const int rowbase = q * 128 + wave * 32;

    sds[tid]       = sdst[bh * 512 + tid];
    sds[tid + 256] = sdst[bh * 512 + tid + 256];

    float si[2];
    const float* arow[2];
    #pragma unroll
    for (int it = 0; it < 2; ++it) {
        int i = rowbase + it * 16 + col;         // A-row m = lane&15
        si[it]   = ssrc[bh * 512 + i];
        arow[it] = adj + ((long)b * 512 + i) * 512;
    }
    __syncthreads();                             // only barrier in k2

    const __bf16* hTb = hT + bh * 64 * 512;
    bf16x8 ones;
    #pragma unroll
    for (int u = 0; u < 8; ++u) ones[u] = (__bf16)1.0f;

    f32x4 acc[2][4] = {};
    f32x4 accs[2]   = {};                        // row sums via P@ones

    // prologue: pa ring depth-2 (ks=0 -> A, ks=1 -> B), bv dbuf (ks=0 -> A)
    float4 paA0[2], paA1[2], paB0[2], paB1[2];
    bf16x8 bvA[4], bvB[4];
    #pragma unroll
    for (int it = 0; it < 2; ++it) {
        paA0[it] = *(const float4*)(arow[it] + quad * 8);
        paA1[it] = *(const float4*)(arow[it] + quad * 8 + 4);
    }
    #pragma unroll
    for (int it = 0; it < 2; ++it) {
        paB0[it] = *(const float4*)(arow[it] + 32 + quad * 8);
        paB1[it] = *(const float4*)(arow[it] + 32 + quad * 8 + 4);
    }
    #pragma unroll
    for (int nt = 0; nt < 4; ++nt)
        bvA[nt] = *(const bf16x8*)(hTb + (long)(nt * 16 + col) * 512 + quad * 8);

    for (int ks = 0; ks < 16; ks += 2) {         // static even/odd dbuf swap
        K2BODY(ks,     paA0, paA1, bvA, bvB)
        K2BODY(ks + 1, paB0, paB1, bvB, bvA)
    }

    // epilogue: accs rows (quad*4+r) align with acc rows
    #pragma unroll
    for (int it = 0; it < 2; ++it)
        #pragma unroll
        for (int r = 0; r < 4; ++r) {
            float s = accs[it][r];
            float inv = (s > 0.f) ? 1.0f / s : 0.f;
            int i = rowbase + it * 16 + quad * 4 + r;
            float* orow = out + ((long)b * 512 + i) * 512 + h * 64;
            #pragma unroll
            for (int nt = 0; nt < 4; ++nt)
                orow[nt * 16 + col] = acc[it][nt][r] * inv;
        }
}

// ---------------- fallback: R8 fused kernel (proven) -----------------------
struct SmemF {
    __bf16 hT[64][HT_STRIDE];
    __bf16 WT[64][WT_STRIDE];
    float  ssrc[512], sdst[512];
    float  asrc[64], adst[64];
};

__global__ __launch_bounds__(1024, 4) void k_gat_fused(const float* __restrict__ x,
                                                       const float* __restrict__ adj,
                                                       const float* __restrict__ W,
                                                       const float* __restrict__ a,
                                                       float* __restrict__ out) {
    __shared__ SmemF sm;
    const int b = blockIdx.x, h = blockIdx.y;
    const int tid  = threadIdx.x;
    const int wave = tid >> 6, lane = tid & 63;
    const int quad = lane >> 4, col = lane & 15;

    if (tid < 128) {
        float v = a[h * 128 + tid] * ESCALE;
        if (tid < 64) sm.asrc[tid] = v; else sm.adst[tid - 64] = v;
    }
    {
        int c = tid & 63, k0 = tid >> 6;
        #pragma unroll 4
        for (int t = 0; t < 16; ++t)
            sm.WT[c][k0 + t * 16] = (__bf16)W[(long)(k0 + t * 16) * 512 + h * 64 + c];
    }
    __syncthreads();
    {
        const float* xb = x + (long)b * 512 * 256;
        f32x4 acc[2][4] = {};
        for (int ks = 0; ks < 8; ++ks) {
            int k0 = ks * 32 + quad * 8;
            bf16x8 av[2], bv[4];
            #pragma unroll
            for (int it = 0; it < 2; ++it)
                av[it] = ld8(xb + (long)(wave * 32 + it * 16 + col) * 256 + k0);
            #pragma unroll
            for (int nt = 0; nt < 4; ++nt)
                bv[nt] = *(const bf16x8*)(&sm.WT[nt * 16 + col][k0]);
            #pragma unroll
            for (int it = 0; it < 2; ++it)
                #pragma unroll
                for (int nt = 0; nt < 4; ++nt)
                    acc[it][nt] = __builtin_amdgcn_mfma_f32_16x16x32_bf16(av[it], bv[nt], acc[it][nt], 0, 0, 0);
        }
        #pragma unroll
        for (int it = 0; it < 2; ++it)
            #pragma unroll
            for (int nt = 0; nt < 4; ++nt) {
                int f = nt * 16 + col;
                int j = wave * 32 + it * 16 + quad * 4;
                bf16x4 pk = { (__bf16)acc[it][nt][0], (__bf16)acc[it][nt][1],
                              (__bf16)acc[it][nt][2], (__bf16)acc[it][nt][3] };
                *(bf16x4*)(&sm.hT[f][j]) = pk;
            }
    }
    __syncthreads();
    {
        int j = tid & 511;
        float s = 0.f;
        if (tid < 512) {
            #pragma unroll 8
            for (int f = 0; f < 64; ++f) s += (float)sm.hT[f][j] * sm.asrc[f];
            sm.ssrc[j] = s;
        } else {
            #pragma unroll 8
            for (int f = 0; f < 64; ++f) s += (float)sm.hT[f][j] * sm.adst[f];
            sm.sdst[j] = s;
        }
    }
    __syncthreads();
    {
        float si[2];
        const float* arow[2];
        #pragma unroll
        for (int it = 0; it < 2; ++it) {
            int i = wave * 32 + it * 16 + col;
            si[it]   = sm.ssrc[i];
            arow[it] = adj + ((long)b * 512 + i) * 512;
        }
        bf16x8 ones;
        #pragma unroll
        for (int u = 0; u < 8; ++u) ones[u] = (__bf16)1.0f;
        f32x4 acc[2][4] = {};
        f32x4 accs[2]   = {};
        float4 pa0[2], pa1[2];
        #pragma unroll
        for (int it = 0; it < 2; ++it) {
            pa0[it] = *(const float4*)(arow[it] + quad * 8);
            pa1[it] = *(const float4*)(arow[it] + quad * 8 + 4);
        }
        for (int ks = 0; ks < 16; ++ks) {
            int j0 = ks * 32 + quad * 8;
            f32x4 s0 = *(const f32x4*)&sm.sdst[j0];
            f32x4 s1 = *(const f32x4*)&sm.sdst[j0 + 4];
            float sd[8] = {s0[0],s0[1],s0[2],s0[3],s1[0],s1[1],s1[2],s1[3]};
            float am[2][8];
            #pragma unroll
            for (int it = 0; it < 2; ++it) {
                am[it][0]=pa0[it].x; am[it][1]=pa0[it].y;
                am[it][2]=pa0[it].z; am[it][3]=pa0[it].w;
                am[it][4]=pa1[it].x; am[it][5]=pa1[it].y;
                am[it][6]=pa1[it].z; am[it][7]=pa1[it].w;
            }
            if (ks < 15) {
                #pragma unroll
                for (int it = 0; it < 2; ++it) {
                    pa0[it] = *(const float4*)(arow[it] + j0 + 32);
                    pa1[it] = *(const float4*)(arow[it] + j0 + 36);
                }
            }
            bf16x8 P[2];
            #pragma unroll
            for (int it = 0; it < 2; ++it)
                #pragma unroll
                for (int u = 0; u < 8; ++u) {
                    float e = si[it] + sd[u];
                    float l = fmaxf(e, ALPHA * e);
                    float p = am[it][u] * EXP2(l);
                    P[it][u] = (__bf16)p;
                }
            bf16x8 bv[4];
            #pragma unroll
            for (int nt = 0; nt < 4; ++nt)
                bv[nt] = *(const bf16x8*)(&sm.hT[nt * 16 + col][j0]);
            #pragma unroll
            for (int it = 0; it < 2; ++it) {
                #pragma unroll
                for (int nt = 0; nt < 4; ++nt)
                    acc[it][nt] = __builtin_amdgcn_mfma_f32_16x16x32_bf16(P[it], bv[nt], acc[it][nt], 0, 0, 0);
                accs[it] = __builtin_amdgcn_mfma_f32_16x16x32_bf16(P[it], ones, accs[it], 0, 0, 0);
            }
        }
        #pragma unroll
        for (int it = 0; it < 2; ++it)
            #pragma unroll
            for (int r = 0; r < 4; ++r) {
                float s = accs[it][r];
                float inv = (s > 0.f) ? 1.0f / s : 0.f;
                int i = wave * 32 + it * 16 + quad * 4 + r;
                float* orow = out + ((long)b * 512 + i) * 512 + h * 64;
                #pragma unroll
                for (int nt = 0; nt < 4; ++nt)
                    orow[nt * 16 + col] = acc[it][nt][r] * inv;
            }
    }
}

// ---------------- launch ---------------------------------------------------
extern "C" void kernel_launch(void* const* d_in, const int* in_sizes, int n_in,
                              void* d_out, int out_size, void* d_ws, size_t ws_size,
                              hipStream_t stream) {
    const float* x   = (const float*)d_in[0];   // (32,512,256)
    const float* adj = (const float*)d_in[1];   // (32,512,512), {0,1}
    const float* W   = (const float*)d_in[2];   // (256,512)
    const float* a   = (const float*)d_in[3];   // (8,128)
    float* out = (float*)d_out;                 // (32,512,512)

    const size_t HT_BYTES = 32ull * 8 * 64 * 512 * 2;      // 16,777,216
    const size_t SC_BYTES = 32ull * 8 * 512 * 4;           //    524,288
    const size_t NEED = HT_BYTES + 2 * SC_BYTES;           // 17,825,792

    if (d_ws && ws_size >= NEED) {
        __bf16* hT  = (__bf16*)d_ws;
        float* ssrc = (float*)((char*)d_ws + HT_BYTES);
        float* sdst = ssrc + 32 * 8 * 512;
        k1_gemm<<<dim3(32, 8, 2), 512, 0, stream>>>(x, W, a, hT, ssrc, sdst);
        k2_attn<<<dim3(32, 8, 4), 256, 0, stream>>>(adj, hT, ssrc, sdst, out);
    } else {
        k_gat_fused<<<dim3(32, 8), 1024, 0, stream>>>(x, adj, W, a, out);
    }
}

// Round 6
// 150.625 us; speedup vs baseline: 1.2877x; 1.2877x over previous
//
#include <hip/hip_runtime.h>
#include <hip/hip_bf16.h>
#include <stdint.h>

// GAT layer, MI355X. B=32, N=512, Fin=256, F=64, H=8. fp32 in / fp32 out.
// R12: kill the scattered global loads (the measured ~4.8k stall-cyc/iter in
// k2: every in-loop load was a 16-row gather, adj re-read 8x = 268MB).
//   k0 (new): adj -> 1-bit mask, coalesced, read adj fp32 EXACTLY once.
//             layout [b][row][quad][ks-bytes 16] so k2 reads 16B/lane.
//   k1: R10's proven GEMM+scores, hT written to ws at stride 520 (pad) so
//       k2 can stage it LINEARLY and still get bank-friendly LDS reads.
//   k2: stage hT(66.5KB)+sdst(2KB) in LDS, mask in 2 dwordx4/lane, then a
//       fully-unrolled 16-step loop with ZERO global loads, ZERO barriers.
//       LDS 68.6KB -> 2 blocks/CU, grid (32,8,2), 16 waves/CU.
// Fallback: if ws_size < 19.2MB, launch the proven R8 fused kernel.

#define ALPHA  0.2f
#define ESCALE 1.4426950408889634f   // log2(e), folded into a at stage 0

typedef __bf16 bf16x8 __attribute__((ext_vector_type(8)));
typedef __bf16 bf16x4 __attribute__((ext_vector_type(4)));
typedef float  f32x4  __attribute__((ext_vector_type(4)));

#if __has_builtin(__builtin_amdgcn_exp2f)
#define EXP2(x) __builtin_amdgcn_exp2f(x)
#else
#define EXP2(x) exp2f(x)
#endif

#define HT_STRIDE 520   // 512+8 pad: bank-spread for k2 LDS reads
#define WT_STRIDE 264   // 256+8

__device__ inline bf16x8 ld8(const float* p) {
    float4 a0 = *(const float4*)p;
    float4 a1 = *(const float4*)(p + 4);
    bf16x8 r;
    r[0]=(__bf16)a0.x; r[1]=(__bf16)a0.y; r[2]=(__bf16)a0.z; r[3]=(__bf16)a0.w;
    r[4]=(__bf16)a1.x; r[5]=(__bf16)a1.y; r[6]=(__bf16)a1.z; r[7]=(__bf16)a1.w;
    return r;
}

// ---------------- k0: adj (fp32 {0,1}) -> bitmask --------------------------
// dword T2 covers bytes ks=4w..4w+3 of row-quad (b,row,quad); bit u of byte
// ks = adj[b][row][ks*32 + quad*8 + u] > 0. Coalesced read & write.
__global__ __launch_bounds__(512) void k0_mask(const float* __restrict__ adj,
                                               unsigned* __restrict__ mask) {
    const int T2 = blockIdx.x * 512 + threadIdx.x;   // 262,144 dwords = 1MB
    const int w    = T2 & 3;
    const int quad = (T2 >> 2) & 3;
    const int row  = (T2 >> 4) & 511;
    const int b    = T2 >> 13;
    const float* p = adj + ((long)b * 512 + row) * 512 + quad * 8;
    unsigned word = 0;
    #pragma unroll
    for (int k = 0; k < 4; ++k) {
        const float* qp = p + (w * 4 + k) * 32;
        float4 a0 = *(const float4*)qp;
        float4 a1 = *(const float4*)(qp + 4);
        unsigned byte =  (a0.x > 0.f ? 1u : 0u)
                      | ((a0.y > 0.f ? 1u : 0u) << 1)
                      | ((a0.z > 0.f ? 1u : 0u) << 2)
                      | ((a0.w > 0.f ? 1u : 0u) << 3)
                      | ((a1.x > 0.f ? 1u : 0u) << 4)
                      | ((a1.y > 0.f ? 1u : 0u) << 5)
                      | ((a1.z > 0.f ? 1u : 0u) << 6)
                      | ((a1.w > 0.f ? 1u : 0u) << 7);
        word |= byte << (8 * k);
    }
    mask[T2] = word;
}

// ---------------- k1: h = x@W (bf16 hT to ws, stride 520) + scores ---------
struct SmemK1 {
    __bf16 WT[64][WT_STRIDE];       // 33,792 B
    float  asrc[64], adst[64];      //    512 B
};                                  // 34,304 B

__global__ __launch_bounds__(512, 4) void k1_gemm(const float* __restrict__ x,
                                                  const float* __restrict__ W,
                                                  const float* __restrict__ a,
                                                  __bf16* __restrict__ hT,
                                                  float* __restrict__ ssrc,
                                                  float* __restrict__ sdst) {
    __shared__ SmemK1 sm;
    const int b = blockIdx.x, h = blockIdx.y;    // b-major: XCD = b%8
    const int tid  = threadIdx.x;                // 512 thr, 8 waves
    const int wave = tid >> 6, lane = tid & 63;
    const int quad = lane >> 4, col = lane & 15;

    if (tid < 128) {
        float v = a[h * 128 + tid] * ESCALE;
        if (tid < 64) sm.asrc[tid] = v; else sm.adst[tid - 64] = v;
    }
    {
        int c = tid & 63, k0 = tid >> 6;
        #pragma unroll 4
        for (int t = 0; t < 32; ++t)
            sm.WT[c][k0 + t * 8] = (__bf16)W[(long)(k0 + t * 8) * 512 + h * 64 + c];
    }
    __syncthreads();                             // only barrier in k1

    f32x4 acc[4][4] = {};
    {
        const float* xb = x + (long)b * 512 * 256;
        for (int ks = 0; ks < 8; ++ks) {         // K = 256
            int k0 = ks * 32 + quad * 8;
            bf16x8 av[4], bv[4];
            #pragma unroll
            for (int it = 0; it < 4; ++it)
                av[it] = ld8(xb + (long)(wave * 64 + it * 16 + col) * 256 + k0);
            #pragma unroll
            for (int nt = 0; nt < 4; ++nt)
                bv[nt] = *(const bf16x8*)(&sm.WT[nt * 16 + col][k0]);
            #pragma unroll
            for (int it = 0; it < 4; ++it)
                #pragma unroll
                for (int nt = 0; nt < 4; ++nt)
                    acc[it][nt] = __builtin_amdgcn_mfma_f32_16x16x32_bf16(av[it], bv[nt], acc[it][nt], 0, 0, 0);
        }
    }

    const long bh = (long)b * 8 + h;
    {
        #pragma unroll
        for (int it = 0; it < 4; ++it)
            #pragma unroll
            for (int nt = 0; nt < 4; ++nt) {
                int f = nt * 16 + col;
                int j = wave * 64 + it * 16 + quad * 4;
                bf16x4 pk = { (__bf16)acc[it][nt][0], (__bf16)acc[it][nt][1],
                              (__bf16)acc[it][nt][2], (__bf16)acc[it][nt][3] };
                *(bf16x4*)(hT + (bh * 64 + f) * HT_STRIDE + j) = pk;
            }
    }

    // scores from fp32 fragments: s[j] = sum_f h[j][f]*a[f]
    {
        float asr[4], adr[4];
        #pragma unroll
        for (int nt = 0; nt < 4; ++nt) {
            asr[nt] = sm.asrc[nt * 16 + col];
            adr[nt] = sm.adst[nt * 16 + col];
        }
        #pragma unroll
        for (int it = 0; it < 4; ++it)
            #pragma unroll
            for (int r = 0; r < 4; ++r) {
                float ps = 0.f, pd = 0.f;
                #pragma unroll
                for (int nt = 0; nt < 4; ++nt) {
                    ps += acc[it][nt][r] * asr[nt];
                    pd += acc[it][nt][r] * adr[nt];
                }
                #pragma unroll
                for (int m = 1; m <= 8; m <<= 1) {   // stays within quad
                    ps += __shfl_xor(ps, m, 64);
                    pd += __shfl_xor(pd, m, 64);
                }
                if (col == 0) {
                    int j = wave * 64 + it * 16 + quad * 4 + r;
                    ssrc[bh * 512 + j] = ps;
                    sdst[bh * 512 + j] = pd;
                }
            }
    }
}

// ---------------- k2: stage 3, all operands LDS/registers ------------------
struct SmemK2 {
    __bf16 hT[64][HT_STRIDE];       // 66,560 B (staged linearly incl. pads)
    float  sds[512];                //  2,048 B
};                                  // 68,608 B -> 2 blocks/CU

__global__ __launch_bounds__(512, 4) void k2_attn(const uint4* __restrict__ mask,
                                                  const __bf16* __restrict__ hT,
                                                  const float* __restrict__ ssrc,
                                                  const float* __restrict__ sdst,
                                                  float* __restrict__ out) {
    __shared__ SmemK2 sm;
    const int b = blockIdx.x, h = blockIdx.y, q = blockIdx.z;
    const int tid  = threadIdx.x;                // 512 thr, 8 waves
    const int wave = tid >> 6, lane = tid & 63;
    const int quad = lane >> 4, col = lane & 15;
    const long bh = (long)b * 8 + h;
    const int rowbase = q * 256 + wave * 32;     // wave owns 32 rows

    // stage hT(b,h): 66,560 B = 4160 x 16B, linear coalesced copy
    {
        const uint4* src = (const uint4*)(hT + bh * 64 * HT_STRIDE);
        uint4* dst = (uint4*)&sm.hT[0][0];
        #pragma unroll
        for (int t = 0; t < 8; ++t)
            dst[t * 512 + tid] = src[t * 512 + tid];
        if (tid < 64) dst[4096 + tid] = src[4096 + tid];
    }
    sm.sds[tid] = sdst[bh * 512 + tid];

    float si[2]; uint4 mk[2];                    // mask: 16B/lane, coalesced
    #pragma unroll
    for (int it = 0; it < 2; ++it) {
        int i = rowbase + it * 16 + col;         // A-row m = lane&15
        si[it] = ssrc[bh * 512 + i];
        mk[it] = mask[((long)b * 512 + i) * 4 + quad];
    }
    __syncthreads();                             // only barrier in k2

    bf16x8 ones;
    #pragma unroll
    for (int u = 0; u < 8; ++u) ones[u] = (__bf16)1.0f;

    f32x4 acc[2][4] = {};
    f32x4 accs[2]   = {};                        // row sums via P@ones

    #pragma unroll
    for (int ks = 0; ks < 16; ++ks) {            // K = 512; zero global/barrier
        const int j0 = ks * 32 + quad * 8;
        f32x4 s0 = *(const f32x4*)&sm.sds[j0];
        f32x4 s1 = *(const f32x4*)&sm.sds[j0 + 4];
        float sd[8] = {s0[0],s0[1],s0[2],s0[3],s1[0],s1[1],s1[2],s1[3]};
        unsigned mb[2];
        #pragma unroll
        for (int it = 0; it < 2; ++it) {         // ks static -> folds
            unsigned wrd = (ks < 4) ? mk[it].x : (ks < 8) ? mk[it].y
                         : (ks < 12) ? mk[it].z : mk[it].w;
            mb[it] = (wrd >> ((ks & 3) * 8)) & 0xFFu;
        }
        bf16x8 P[2];
        #pragma unroll
        for (int it = 0; it < 2; ++it)
            #pragma unroll
            for (int u = 0; u < 8; ++u) {
                float e = si[it] + sd[u];        // pre-scaled by log2e
                float l = fmaxf(e, ALPHA * e);   // lrelu
                float xv = EXP2(l);
                P[it][u] = (__bf16)(((mb[it] >> u) & 1u) ? xv : 0.0f);
            }
        bf16x8 bv[4];
        #pragma unroll
        for (int nt = 0; nt < 4; ++nt)
            bv[nt] = *(const bf16x8*)(&sm.hT[nt * 16 + col][j0]);
        #pragma unroll
        for (int it = 0; it < 2; ++it) {
            #pragma unroll
            for (int nt = 0; nt < 4; ++nt)
                acc[it][nt] = __builtin_amdgcn_mfma_f32_16x16x32_bf16(P[it], bv[nt], acc[it][nt], 0, 0, 0);
            accs[it] = __builtin_amdgcn_mfma_f32_16x16x32_bf16(P[it], ones, accs[it], 0, 0, 0);
        }
    }
    // epilogue: accs rows (quad*4+r) align with acc rows
    #pragma unroll
    for (int it = 0; it < 2; ++it)
        #pragma unroll
        for (int r = 0; r < 4; ++r) {
            float s = accs[it][r];
            float inv = (s > 0.f) ? 1.0f / s : 0.f;
            int i = rowbase + it * 16 + quad * 4 + r;
            float* orow = out + ((long)b * 512 + i) * 512 + h * 64;
            #pragma unroll
            for (int nt = 0; nt < 4; ++nt)
                orow[nt * 16 + col] = acc[it][nt][r] * inv;
        }
}

// ---------------- fallback: R8 fused kernel (proven) -----------------------
struct SmemF {
    __bf16 hT[64][HT_STRIDE];
    __bf16 WT[64][WT_STRIDE];
    float  ssrc[512], sdst[512];
    float  asrc[64], adst[64];
};

__global__ __launch_bounds__(1024, 4) void k_gat_fused(const float* __restrict__ x,
                                                       const float* __restrict__ adj,
                                                       const float* __restrict__ W,
                                                       const float* __restrict__ a,
                                                       float* __restrict__ out) {
    __shared__ SmemF sm;
    const int b = blockIdx.x, h = blockIdx.y;
    const int tid  = threadIdx.x;
    const int wave = tid >> 6, lane = tid & 63;
    const int quad = lane >> 4, col = lane & 15;

    if (tid < 128) {
        float v = a[h * 128 + tid] * ESCALE;
        if (tid < 64) sm.asrc[tid] = v; else sm.adst[tid - 64] = v;
    }
    {
        int c = tid & 63, k0 = tid >> 6;
        #pragma unroll 4
        for (int t = 0; t < 16; ++t)
            sm.WT[c][k0 + t * 16] = (__bf16)W[(long)(k0 + t * 16) * 512 + h * 64 + c];
    }
    __syncthreads();
    {
        const float* xb = x + (long)b * 512 * 256;
        f32x4 acc[2][4] = {};
        for (int ks = 0; ks < 8; ++ks) {
            int k0 = ks * 32 + quad * 8;
            bf16x8 av[2], bv[4];
            #pragma unroll
            for (int it = 0; it < 2; ++it)
                av[it] = ld8(xb + (long)(wave * 32 + it * 16 + col) * 256 + k0);
            #pragma unroll
            for (int nt = 0; nt < 4; ++nt)
                bv[nt] = *(const bf16x8*)(&sm.WT[nt * 16 + col][k0]);
            #pragma unroll
            for (int it = 0; it < 2; ++it)
                #pragma unroll
                for (int nt = 0; nt < 4; ++nt)
                    acc[it][nt] = __builtin_amdgcn_mfma_f32_16x16x32_bf16(av[it], bv[nt], acc[it][nt], 0, 0, 0);
        }
        #pragma unroll
        for (int it = 0; it < 2; ++it)
            #pragma unroll
            for (int nt = 0; nt < 4; ++nt) {
                int f = nt * 16 + col;
                int j = wave * 32 + it * 16 + quad * 4;
                bf16x4 pk = { (__bf16)acc[it][nt][0], (__bf16)acc[it][nt][1],
                              (__bf16)acc[it][nt][2], (__bf16)acc[it][nt][3] };
                *(bf16x4*)(&sm.hT[f][j]) = pk;
            }
    }
    __syncthreads();
    {
        int j = tid & 511;
        float s = 0.f;
        if (tid < 512) {
            #pragma unroll 8
            for (int f = 0; f < 64; ++f) s += (float)sm.hT[f][j] * sm.asrc[f];
            sm.ssrc[j] = s;
        } else {
            #pragma unroll 8
            for (int f = 0; f < 64; ++f) s += (float)sm.hT[f][j] * sm.adst[f];
            sm.sdst[j] = s;
        }
    }
    __syncthreads();
    {
        float si[2];
        const float* arow[2];
        #pragma unroll
        for (int it = 0; it < 2; ++it) {
            int i = wave * 32 + it * 16 + col;
            si[it]   = sm.ssrc[i];
            arow[it] = adj + ((long)b * 512 + i) * 512;
        }
        bf16x8 ones;
        #pragma unroll
        for (int u = 0; u < 8; ++u) ones[u] = (__bf16)1.0f;
        f32x4 acc[2][4] = {};
        f32x4 accs[2]   = {};
        float4 pa0[2], pa1[2];
        #pragma unroll
        for (int it = 0; it < 2; ++it) {
            pa0[it] = *(const float4*)(arow[it] + quad * 8);
            pa1[it] = *(const float4*)(arow[it] + quad * 8 + 4);
        }
        for (int ks = 0; ks < 16; ++ks) {
            int j0 = ks * 32 + quad * 8;
            f32x4 s0 = *(const f32x4*)&sm.sdst[j0];
            f32x4 s1 = *(const f32x4*)&sm.sdst[j0 + 4];
            float sd[8] = {s0[0],s0[1],s0[2],s0[3],s1[0],s1[1],s1[2],s1[3]};
            float am[2][8];
            #pragma unroll
            for (int it = 0; it < 2; ++it) {
                am[it][0]=pa0[it].x; am[it][1]=pa0[it].y;
                am[it][2]=pa0[it].z; am[it][3]=pa0[it].w;
                am[it][4]=pa1[it].x; am[it][5]=pa1[it].y;
                am[it][6]=pa1[it].z; am[it][7]=pa1[it].w;
            }
            if (ks < 15) {
                #pragma unroll
                for (int it = 0; it < 2; ++it) {
                    pa0[it] = *(const float4*)(arow[it] + j0 + 32);
                    pa1[it] = *(const float4*)(arow[it] + j0 + 36);
                }
            }
            bf16x8 P[2];
            #pragma unroll
            for (int it = 0; it < 2; ++it)
                #pragma unroll
                for (int u = 0; u < 8; ++u) {
                    float e = si[it] + sd[u];
                    float l = fmaxf(e, ALPHA * e);
                    float p = am[it][u] * EXP2(l);
                    P[it][u] = (__bf16)p;
                }
            bf16x8 bv[4];
            #pragma unroll
            for (int nt = 0; nt < 4; ++nt)
                bv[nt] = *(const bf16x8*)(&sm.hT[nt * 16 + col][j0]);
            #pragma unroll
            for (int it = 0; it < 2; ++it) {
                #pragma unroll
                for (int nt = 0; nt < 4; ++nt)
                    acc[it][nt] = __builtin_amdgcn_mfma_f32_16x16x32_bf16(P[it], bv[nt], acc[it][nt], 0, 0, 0);
                accs[it] = __builtin_amdgcn_mfma_f32_16x16x32_bf16(P[it], ones, accs[it], 0, 0, 0);
            }
        }
        #pragma unroll
        for (int it = 0; it < 2; ++it)
            #pragma unroll
            for (int r = 0; r < 4; ++r) {
                float s = accs[it][r];
                float inv = (s > 0.f) ? 1.0f / s : 0.f;
                int i = wave * 32 + it * 16 + quad * 4 + r;
                float* orow = out + ((long)b * 512 + i) * 512 + h * 64;
                #pragma unroll
                for (int nt = 0; nt < 4; ++nt)
                    orow[nt * 16 + col] = acc[it][nt][r] * inv;
            }
    }
}

// ---------------- launch ---------------------------------------------------
extern "C" void kernel_launch(void* const* d_in, const int* in_sizes, int n_in,
                              void* d_out, int out_size, void* d_ws, size_t ws_size,
                              hipStream_t stream) {
    const float* x   = (const float*)d_in[0];   // (32,512,256)
    const float* adj = (const float*)d_in[1];   // (32,512,512), {0,1}
    const float* W   = (const float*)d_in[2];   // (256,512)
    const float* a   = (const float*)d_in[3];   // (8,128)
    float* out = (float*)d_out;                 // (32,512,512)

    const size_t HT_BYTES   = 256ull * 64 * HT_STRIDE * 2;   // 17,039,360
    const size_t SC_BYTES   = 32ull * 8 * 512 * 4;           //    524,288
    const size_t MASK_BYTES = 32ull * 512 * 64;              //  1,048,576
    const size_t NEED = HT_BYTES + 2 * SC_BYTES + MASK_BYTES;// 19,136,512

    if (d_ws && ws_size >= NEED) {
        __bf16* hT   = (__bf16*)d_ws;
        float* ssrc  = (float*)((char*)d_ws + HT_BYTES);
        float* sdst  = ssrc + 32 * 8 * 512;
        unsigned* mk = (unsigned*)((char*)d_ws + HT_BYTES + 2 * SC_BYTES);
        k0_mask<<<512, 512, 0, stream>>>(adj, mk);
        k1_gemm<<<dim3(32, 8), 512, 0, stream>>>(x, W, a, hT, ssrc, sdst);
        k2_attn<<<dim3(32, 8, 2), 512, 0, stream>>>((const uint4*)mk, hT, ssrc, sdst, out);
    } else {
        k_gat_fused<<<dim3(32, 8), 1024, 0, stream>>>(x, adj, W, a, out);
    }
}